// Round 9
// baseline (448.456 us; speedup 1.0000x reference)
//
#include <hip/hip_runtime.h>
#include <hip/hip_bf16.h>

typedef unsigned short u16;
typedef unsigned int u32;
typedef __bf16 bf16x8 __attribute__((ext_vector_type(8)));
typedef float f32x4 __attribute__((ext_vector_type(4)));
typedef u32 u32x2 __attribute__((ext_vector_type(2)));

#define AS1 __attribute__((address_space(1)))
#define AS3 __attribute__((address_space(3)))

__device__ __forceinline__ void gload16(const void* gp, void* lp) {
    __builtin_amdgcn_global_load_lds((const AS1 u32*)gp, (AS3 u32*)lp, 16, 0, 0);
}

__device__ __forceinline__ u16 f2b(float f) {
    __bf16 h = (__bf16)f;
    return __builtin_bit_cast(u16, h);
}

// ---------------- fused prep: x->bf16 convert + 4 weight transposes ----------------
__global__ __launch_bounds__(256) void prep_kernel(const float* __restrict__ x,
                                                   const float* __restrict__ wq,
                                                   const float* __restrict__ wk,
                                                   const float* __restrict__ wv,
                                                   const float* __restrict__ wo,
                                                   u16* __restrict__ xb,
                                                   u16* __restrict__ wT,
                                                   u16* __restrict__ woT) {
    __shared__ u16 tile[32][33];
    const int bid = blockIdx.x, tid = threadIdx.x;
    if (bid < 8192) {
        int i = bid * 256 + tid;
        f32x4 v = *(const f32x4*)(x + (size_t)i * 4);
        u32x2 o;
        o[0] = (u32)f2b(v[0]) | ((u32)f2b(v[1]) << 16);
        o[1] = (u32)f2b(v[2]) | ((u32)f2b(v[3]) << 16);
        *(u32x2*)(xb + (size_t)i * 4) = o;
        return;
    }
    const float* in;
    u16* out;
    int C, t;
    if (bid < 12288) { t = bid - 8192; in = wq; out = wT; C = 2048; }
    else if (bid < 13312) { t = bid - 12288; in = wk; out = wT + 2048 * 2048; C = 512; }
    else if (bid < 14336) { t = bid - 13312; in = wv; out = wT + 2560 * 2048; C = 512; }
    else { t = bid - 14336; in = wo; out = woT; C = 2048; }
    const int nbx = C >> 5;
    const int bx = (t % nbx) * 32, by = (t / nbx) * 32;
    const int tx = tid & 31, ty = tid >> 5;
#pragma unroll
    for (int i = 0; i < 32; i += 8)
        tile[ty + i][tx] = f2b(in[(size_t)(by + ty + i) * C + bx + tx]);
    __syncthreads();
#pragma unroll
    for (int i = 0; i < 32; i += 8)
        out[(size_t)(bx + ty + i) * 2048 + by + tx] = tile[tx][ty + i];
}

// ---------------- transpose V section of qkv -> vT[b][kvh][d][s] ----------------
__global__ __launch_bounds__(256) void transpose_v(const u16* __restrict__ qkv,
                                                   u16* __restrict__ vT) {
    __shared__ u16 tile[32][33];
    const int bx = blockIdx.x * 32;
    const int by = blockIdx.y * 32;
    const int tx = threadIdx.x & 31, ty = threadIdx.x >> 5;
#pragma unroll
    for (int i = 0; i < 32; i += 8)
        tile[ty + i][tx] = qkv[(size_t)(by + ty + i) * 3072 + 2560 + bx + tx];
    __syncthreads();
    const int b = by >> 11, s0 = by & 2047;
#pragma unroll
    for (int i = 0; i < 32; i += 8)
        vT[(size_t)(b * 512 + bx + ty + i) * 2048 + s0 + tx] = tile[tx][ty + i];
}

// ---------------- GEMM: C[M][ldc slice] = A[M][K] * Bt[N][K]^T, bf16 in, OT out ----------------
template <typename OT, bool ROPE>
__global__ __launch_bounds__(256) void gemm_bt(const __bf16* __restrict__ A,
                                               const __bf16* __restrict__ Bt,
                                               OT* __restrict__ C,
                                               int K, int ldc,
                                               const float* __restrict__ fc,
                                               const float* __restrict__ fs) {
    __shared__ __align__(16) __bf16 Al[128 * 32];
    __shared__ __align__(16) __bf16 Bl[128 * 32];
    const int tid = threadIdx.x;
    const int lane = tid & 63, w = tid >> 6;
    const int wm = w >> 1, wn = w & 1;
    const int ln15 = lane & 15, lg = lane >> 4;
    const int nwg = gridDim.x * gridDim.y;
    const int lid = blockIdx.y * gridDim.x + blockIdx.x;
    const int swz = (lid & 7) * (nwg >> 3) + (lid >> 3);
    const int bm = swz / gridDim.x, bn = swz % gridDim.x;

    const f32x4 fzero = {0.f, 0.f, 0.f, 0.f};
    f32x4 acc[4][4];
#pragma unroll
    for (int m = 0; m < 4; m++)
#pragma unroll
        for (int n = 0; n < 4; n++) acc[m][n] = fzero;

    const __bf16* Ab = A + (size_t)(bm * 128) * K;
    const __bf16* Bb = Bt + (size_t)(bn * 128) * K;

    for (int k0 = 0; k0 < K; k0 += 32) {
#pragma unroll
        for (int i = 0; i < 2; i++) {
            int gid = i * 256 + tid;
            int row = gid >> 2, gc = gid & 3;
            gload16(Ab + (size_t)row * K + k0 + gc * 8, (char*)Al + gid * 16);
            gload16(Bb + (size_t)row * K + k0 + gc * 8, (char*)Bl + gid * 16);
        }
        __syncthreads();
        bf16x8 af[4], bfr[4];
#pragma unroll
        for (int m = 0; m < 4; m++)
            af[m] = *(const bf16x8*)&Al[(wm * 64 + m * 16 + ln15) * 32 + lg * 8];
#pragma unroll
        for (int n = 0; n < 4; n++)
            bfr[n] = *(const bf16x8*)&Bl[(wn * 64 + n * 16 + ln15) * 32 + lg * 8];
#pragma unroll
        for (int m = 0; m < 4; m++)
#pragma unroll
            for (int n = 0; n < 4; n++)
                acc[m][n] = __builtin_amdgcn_mfma_f32_16x16x32_bf16(af[m], bfr[n], acc[m][n], 0, 0, 0);
        __syncthreads();
    }

    if (ROPE) {
#pragma unroll
        for (int n = 0; n < 4; n++) {
            const int col = bn * 128 + wn * 64 + n * 16 + ln15;
            if (col < 2560) {
                const int p = (col & 127) >> 1;
                const bool odd = (col & 1) != 0;
#pragma unroll
                for (int m = 0; m < 4; m++)
#pragma unroll
                    for (int r = 0; r < 4; r++) {
                        const int row = bm * 128 + wm * 64 + m * 16 + lg * 4 + r;
                        const int sp = row & 2047;
                        float c = fc[sp * 64 + p];
                        float sn = fs[sp * 64 + p];
                        float v = acc[m][n][r];
                        float v2 = __shfl_xor(v, 1);
                        acc[m][n][r] = odd ? (v2 * sn + v * c) : (v * c - v2 * sn);
                    }
            }
        }
    }

#pragma unroll
    for (int m = 0; m < 4; m++)
#pragma unroll
        for (int n = 0; n < 4; n++)
#pragma unroll
            for (int r = 0; r < 4; r++) {
                int row = bm * 128 + wm * 64 + m * 16 + lg * 4 + r;
                int col = bn * 128 + wn * 64 + n * 16 + ln15;
                C[(size_t)row * ldc + col] = (OT)acc[m][n][r];
            }
}

// ---------------- flash attention, causal, GQA rep=4 ----------------
// 512 blocks (LPT decode: heavy first), 256 threads = 4 waves x 32 q-rows, KVBLK=64.
// LDS 64 KB (K single-buf 16K + V dbuf 32K + P 16K) -> true 2 blocks/CU.
// Per tile: QK | bar | stage K(t+1)+V(t+1) overlapping softmax+PV | bar.
__global__ __launch_bounds__(256) void attn_kernel(const __bf16* __restrict__ qkv,
                                                   const __bf16* __restrict__ vT,
                                                   __bf16* __restrict__ ctx) {
    __shared__ __align__(16) __bf16 Klds[64 * 128];      // [kv][d], granule g at g^(kv&7)
    __shared__ __align__(16) __bf16 VTlds[2][128 * 64];  // [d][kv], granule g at g^(d&7)
    __shared__ __align__(16) __bf16 Plds[4][32 * 64];    // per wave [32 q][64 kv], granule g at g^(q&7)

    const int tid = threadIdx.x, lane = tid & 63, w = tid >> 6;
    const int ln15 = lane & 15, lg = lane >> 4;
    int i = blockIdx.x, qblk, hb;
    if (i < 256) { qblk = 15 - (i >> 5); hb = i & 31; }
    else { int j = i - 256; qblk = j >> 5; hb = j & 31; }
    const int h = hb >> 1, b = hb & 1;
    const int kvh = h >> 2;
    const int qw0 = qblk * 128 + w * 32;
    const float c1 = 0.08838834764831845f * 1.4426950408889634f;  // scale * log2(e)

    const __bf16* qbase = qkv + (size_t)(b * 2048 + qw0 + ln15) * 3072 + h * 128;
    bf16x8 aq[2][4];
#pragma unroll
    for (int m = 0; m < 2; m++)
#pragma unroll
        for (int c = 0; c < 4; c++)
            aq[m][c] = *(const bf16x8*)(qbase + (size_t)m * 16 * 3072 + c * 32 + lg * 8);

    const __bf16* Kg = qkv + (size_t)(b * 2048) * 3072 + 2048 + kvh * 128;
    const __bf16* Vg = vT + (size_t)((b * 4 + kvh) * 128) * 2048;

    const f32x4 fzero = {0.f, 0.f, 0.f, 0.f};
    float m_run[8], l_run[8];   // i = m*4 + r
    f32x4 acc[2][8];
#pragma unroll
    for (int i2 = 0; i2 < 8; i2++) { m_run[i2] = -1e30f; l_run[i2] = 0.f; }
#pragma unroll
    for (int m = 0; m < 2; m++)
#pragma unroll
        for (int dt = 0; dt < 8; dt++) acc[m][dt] = fzero;

    const int nt = 2 * qblk + 2;

#define STAGE_K(t)                                                                        \
    do {                                                                                  \
        const int kb_ = (t) * 64;                                                         \
        _Pragma("unroll") for (int i2 = 0; i2 < 4; i2++) {                                \
            int gid = i2 * 256 + tid;                                                     \
            int kv = gid >> 4, sl = gid & 15;                                             \
            gload16(Kg + (size_t)(kb_ + kv) * 3072 + ((sl ^ (kv & 7)) * 8),               \
                    (char*)Klds + gid * 16);                                              \
        }                                                                                 \
    } while (0)
#define STAGE_V(buf, t)                                                                   \
    do {                                                                                  \
        const int kb_ = (t) * 64;                                                         \
        _Pragma("unroll") for (int i2 = 0; i2 < 4; i2++) {                                \
            int gid = i2 * 256 + tid;                                                     \
            int d = gid >> 3, sl = gid & 7;                                               \
            gload16(Vg + (size_t)d * 2048 + kb_ + ((sl ^ (d & 7)) * 8),                   \
                    (char*)VTlds[buf] + gid * 16);                                        \
        }                                                                                 \
    } while (0)

    STAGE_K(0);
    STAGE_V(0, 0);
    __syncthreads();

    int cur = 0;
    for (int t = 0; t < nt; t++) {
        const int kbase = t * 64;
        const bool active = (kbase <= qw0 + 31);

        f32x4 st[2][4];
        if (active) {
            // QK^T : S[32 q][64 kv]
#pragma unroll
            for (int ct = 0; ct < 4; ct++) {
                int kv = ct * 16 + ln15;
                f32x4 s0 = fzero, s1 = fzero;
#pragma unroll
                for (int c = 0; c < 4; c++) {
                    int g = c * 4 + lg;
                    bf16x8 bk = *(const bf16x8*)&Klds[kv * 128 + ((g ^ (kv & 7)) * 8)];
                    s0 = __builtin_amdgcn_mfma_f32_16x16x32_bf16(aq[0][c], bk, s0, 0, 0, 0);
                    s1 = __builtin_amdgcn_mfma_f32_16x16x32_bf16(aq[1][c], bk, s1, 0, 0, 0);
                }
                st[0][ct] = s0;
                st[1][ct] = s1;
            }
        }
        __syncthreads();  // all waves done reading Klds
        if (t + 1 < nt) { STAGE_K(t + 1); STAGE_V(cur ^ 1, t + 1); }  // overlap softmax+PV

        if (active) {
            // causal mask (diagonal tiles only)
            if (kbase + 63 > qw0) {
#pragma unroll
                for (int m = 0; m < 2; m++)
#pragma unroll
                    for (int ct = 0; ct < 4; ct++) {
                        int kvi = kbase + ct * 16 + ln15;
#pragma unroll
                        for (int r = 0; r < 4; r++) {
                            int qi = qw0 + m * 16 + lg * 4 + r;
                            if (kvi > qi) st[m][ct][r] = -1e30f;
                        }
                    }
            }
            // ---- softmax, ILP phase-split (8 rows' chains interleaved) ----
            float tm[8];
#pragma unroll
            for (int m = 0; m < 2; m++)
#pragma unroll
                for (int r = 0; r < 4; r++)
                    tm[m * 4 + r] = fmaxf(fmaxf(st[m][0][r], st[m][1][r]),
                                          fmaxf(st[m][2][r], st[m][3][r]));
#pragma unroll
            for (int off = 1; off < 16; off <<= 1)
#pragma unroll
                for (int i2 = 0; i2 < 8; i2++)
                    tm[i2] = fmaxf(tm[i2], __shfl_xor(tm[i2], off, 16));
            float corr[8];
#pragma unroll
            for (int i2 = 0; i2 < 8; i2++) {
                float mn = fmaxf(m_run[i2], tm[i2]);
                corr[i2] = exp2f((m_run[i2] - mn) * c1);
                m_run[i2] = mn;
            }
            float ts[8];
#pragma unroll
            for (int m = 0; m < 2; m++)
#pragma unroll
                for (int r = 0; r < 4; r++) {
                    const int i2 = m * 4 + r;
                    const int q = m * 16 + lg * 4 + r;
                    float s = 0.f;
#pragma unroll
                    for (int ct = 0; ct < 4; ct++) {
                        float p = exp2f((st[m][ct][r] - m_run[i2]) * c1);
                        s += p;
                        int pg = ct * 2 + (ln15 >> 3);
                        Plds[w][q * 64 + ((pg ^ (q & 7)) * 8) + (ln15 & 7)] = (__bf16)p;
                    }
                    ts[i2] = s;
                }
#pragma unroll
            for (int off = 1; off < 16; off <<= 1)
#pragma unroll
                for (int i2 = 0; i2 < 8; i2++)
                    ts[i2] += __shfl_xor(ts[i2], off, 16);
#pragma unroll
            for (int i2 = 0; i2 < 8; i2++) l_run[i2] = l_run[i2] * corr[i2] + ts[i2];
#pragma unroll
            for (int m = 0; m < 2; m++)
#pragma unroll
                for (int dt = 0; dt < 8; dt++)
#pragma unroll
                    for (int r = 0; r < 4; r++) acc[m][dt][r] *= corr[m * 4 + r];
            // ---- PV : O[32 q][128 d] += P[32][64] * V[64][128] ----
#pragma unroll
            for (int s2 = 0; s2 < 2; s2++) {
                const int kvg = s2 * 4 + lg;
                bf16x8 pa0 = *(const bf16x8*)&Plds[w][(0 * 16 + ln15) * 64 + ((kvg ^ (ln15 & 7)) * 8)];
                bf16x8 pa1 = *(const bf16x8*)&Plds[w][(1 * 16 + ln15) * 64 + ((kvg ^ (ln15 & 7)) * 8)];
#pragma unroll
                for (int dt = 0; dt < 8; dt++) {
                    int d = dt * 16 + ln15;
                    bf16x8 bv = *(const bf16x8*)&VTlds[cur][d * 64 + ((kvg ^ (d & 7)) * 8)];
                    acc[0][dt] = __builtin_amdgcn_mfma_f32_16x16x32_bf16(pa0, bv, acc[0][dt], 0, 0, 0);
                    acc[1][dt] = __builtin_amdgcn_mfma_f32_16x16x32_bf16(pa1, bv, acc[1][dt], 0, 0, 0);
                }
            }
        }
        __syncthreads();  // drains staged K/V; Klds,VTlds[cur^1] ready
        cur ^= 1;
    }
#undef STAGE_K
#undef STAGE_V

    // epilogue: O / l -> ctx
    __bf16* crow = ctx + (size_t)(b * 2048 + qw0) * 2048 + h * 128;
#pragma unroll
    for (int m = 0; m < 2; m++)
#pragma unroll
        for (int dt = 0; dt < 8; dt++)
#pragma unroll
            for (int r = 0; r < 4; r++) {
                float v = acc[m][dt][r] / l_run[m * 4 + r];
                crow[(size_t)(m * 16 + lg * 4 + r) * 2048 + dt * 16 + ln15] = (__bf16)v;
            }
}

extern "C" void kernel_launch(void* const* d_in, const int* in_sizes, int n_in,
                              void* d_out, int out_size, void* d_ws, size_t ws_size,
                              hipStream_t stream) {
    const float* x = (const float*)d_in[0];
    const float* fc = (const float*)d_in[1];
    const float* fs = (const float*)d_in[2];
    const float* wq = (const float*)d_in[3];
    const float* wk = (const float*)d_in[4];
    const float* wv = (const float*)d_in[5];
    const float* wo = (const float*)d_in[6];
    float* out = (float*)d_out;

    char* ws = (char*)d_ws;
    __bf16* wT  = (__bf16*)ws;                        // [3072][2048]
    __bf16* woT = (__bf16*)(ws + 12582912);           // [2048][2048]
    __bf16* xb  = (__bf16*)(ws + 20971520);           // [4096][2048]
    __bf16* qkv = (__bf16*)(ws + 37748736);           // [4096][3072]
    __bf16* ctx = (__bf16*)(ws + 62914560);           // [4096][2048]
    __bf16* vT  = xb;                                 // reuse xb: [2][4][128][2048]

    prep_kernel<<<18432, 256, 0, stream>>>(x, wq, wk, wv, wo, (u16*)xb, (u16*)wT, (u16*)woT);

    gemm_bt<__bf16, true><<<dim3(24, 32), 256, 0, stream>>>(xb, wT, qkv, 2048, 3072, fc, fs);

    transpose_v<<<dim3(16, 128), 256, 0, stream>>>((const u16*)qkv, (u16*)vT);

    attn_kernel<<<512, 256, 0, stream>>>(qkv, vT, ctx);

    gemm_bt<float, false><<<dim3(16, 32), 256, 0, stream>>>(ctx, woT, out, 2048, 2048, nullptr, nullptr);
}

// Round 10
// 399.459 us; speedup vs baseline: 1.1227x; 1.1227x over previous
//
#include <hip/hip_runtime.h>
#include <hip/hip_bf16.h>

typedef unsigned short u16;
typedef unsigned int u32;
typedef __bf16 bf16x8 __attribute__((ext_vector_type(8)));
typedef float f32x4 __attribute__((ext_vector_type(4)));
typedef u32 u32x2 __attribute__((ext_vector_type(2)));

#define AS1 __attribute__((address_space(1)))
#define AS3 __attribute__((address_space(3)))

__device__ __forceinline__ void gload16(const void* gp, void* lp) {
    __builtin_amdgcn_global_load_lds((const AS1 u32*)gp, (AS3 u32*)lp, 16, 0, 0);
}

__device__ __forceinline__ u16 f2b(float f) {
    __bf16 h = (__bf16)f;
    return __builtin_bit_cast(u16, h);
}

// ---------------- fused prep: x->bf16 convert + 4 weight transposes ----------------
__global__ __launch_bounds__(256) void prep_kernel(const float* __restrict__ x,
                                                   const float* __restrict__ wq,
                                                   const float* __restrict__ wk,
                                                   const float* __restrict__ wv,
                                                   const float* __restrict__ wo,
                                                   u16* __restrict__ xb,
                                                   u16* __restrict__ wT,
                                                   u16* __restrict__ woT) {
    __shared__ u16 tile[32][33];
    const int bid = blockIdx.x, tid = threadIdx.x;
    if (bid < 8192) {
        int i = bid * 256 + tid;
        f32x4 v = *(const f32x4*)(x + (size_t)i * 4);
        u32x2 o;
        o[0] = (u32)f2b(v[0]) | ((u32)f2b(v[1]) << 16);
        o[1] = (u32)f2b(v[2]) | ((u32)f2b(v[3]) << 16);
        *(u32x2*)(xb + (size_t)i * 4) = o;
        return;
    }
    const float* in;
    u16* out;
    int C, t;
    if (bid < 12288) { t = bid - 8192; in = wq; out = wT; C = 2048; }
    else if (bid < 13312) { t = bid - 12288; in = wk; out = wT + 2048 * 2048; C = 512; }
    else if (bid < 14336) { t = bid - 13312; in = wv; out = wT + 2560 * 2048; C = 512; }
    else { t = bid - 14336; in = wo; out = woT; C = 2048; }
    const int nbx = C >> 5;
    const int bx = (t % nbx) * 32, by = (t / nbx) * 32;
    const int tx = tid & 31, ty = tid >> 5;
#pragma unroll
    for (int i = 0; i < 32; i += 8)
        tile[ty + i][tx] = f2b(in[(size_t)(by + ty + i) * C + bx + tx]);
    __syncthreads();
#pragma unroll
    for (int i = 0; i < 32; i += 8)
        out[(size_t)(bx + ty + i) * 2048 + by + tx] = tile[tx][ty + i];
}

// ---------------- transpose V section of qkv -> vT[b][kvh][d][s] ----------------
__global__ __launch_bounds__(256) void transpose_v(const u16* __restrict__ qkv,
                                                   u16* __restrict__ vT) {
    __shared__ u16 tile[32][33];
    const int bx = blockIdx.x * 32;
    const int by = blockIdx.y * 32;
    const int tx = threadIdx.x & 31, ty = threadIdx.x >> 5;
#pragma unroll
    for (int i = 0; i < 32; i += 8)
        tile[ty + i][tx] = qkv[(size_t)(by + ty + i) * 3072 + 2560 + bx + tx];
    __syncthreads();
    const int b = by >> 11, s0 = by & 2047;
#pragma unroll
    for (int i = 0; i < 32; i += 8)
        vT[(size_t)(b * 512 + bx + ty + i) * 2048 + s0 + tx] = tile[tx][ty + i];
}

// ---------------- GEMM: C[M][ldc slice] = A[M][K] * Bt[N][K]^T, bf16 in, OT out ----------------
template <typename OT, bool ROPE>
__global__ __launch_bounds__(256) void gemm_bt(const __bf16* __restrict__ A,
                                               const __bf16* __restrict__ Bt,
                                               OT* __restrict__ C,
                                               int K, int ldc,
                                               const float* __restrict__ fc,
                                               const float* __restrict__ fs) {
    __shared__ __align__(16) __bf16 Al[128 * 32];
    __shared__ __align__(16) __bf16 Bl[128 * 32];
    const int tid = threadIdx.x;
    const int lane = tid & 63, w = tid >> 6;
    const int wm = w >> 1, wn = w & 1;
    const int ln15 = lane & 15, lg = lane >> 4;
    const int nwg = gridDim.x * gridDim.y;
    const int lid = blockIdx.y * gridDim.x + blockIdx.x;
    const int swz = (lid & 7) * (nwg >> 3) + (lid >> 3);
    const int bm = swz / gridDim.x, bn = swz % gridDim.x;

    const f32x4 fzero = {0.f, 0.f, 0.f, 0.f};
    f32x4 acc[4][4];
#pragma unroll
    for (int m = 0; m < 4; m++)
#pragma unroll
        for (int n = 0; n < 4; n++) acc[m][n] = fzero;

    const __bf16* Ab = A + (size_t)(bm * 128) * K;
    const __bf16* Bb = Bt + (size_t)(bn * 128) * K;

    for (int k0 = 0; k0 < K; k0 += 32) {
#pragma unroll
        for (int i = 0; i < 2; i++) {
            int gid = i * 256 + tid;
            int row = gid >> 2, gc = gid & 3;
            gload16(Ab + (size_t)row * K + k0 + gc * 8, (char*)Al + gid * 16);
            gload16(Bb + (size_t)row * K + k0 + gc * 8, (char*)Bl + gid * 16);
        }
        __syncthreads();
        bf16x8 af[4], bfr[4];
#pragma unroll
        for (int m = 0; m < 4; m++)
            af[m] = *(const bf16x8*)&Al[(wm * 64 + m * 16 + ln15) * 32 + lg * 8];
#pragma unroll
        for (int n = 0; n < 4; n++)
            bfr[n] = *(const bf16x8*)&Bl[(wn * 64 + n * 16 + ln15) * 32 + lg * 8];
#pragma unroll
        for (int m = 0; m < 4; m++)
#pragma unroll
            for (int n = 0; n < 4; n++)
                acc[m][n] = __builtin_amdgcn_mfma_f32_16x16x32_bf16(af[m], bfr[n], acc[m][n], 0, 0, 0);
        __syncthreads();
    }

    if (ROPE) {
#pragma unroll
        for (int n = 0; n < 4; n++) {
            const int col = bn * 128 + wn * 64 + n * 16 + ln15;
            if (col < 2560) {
                const int p = (col & 127) >> 1;
                const bool odd = (col & 1) != 0;
#pragma unroll
                for (int m = 0; m < 4; m++)
#pragma unroll
                    for (int r = 0; r < 4; r++) {
                        const int row = bm * 128 + wm * 64 + m * 16 + lg * 4 + r;
                        const int sp = row & 2047;
                        float c = fc[sp * 64 + p];
                        float sn = fs[sp * 64 + p];
                        float v = acc[m][n][r];
                        float v2 = __shfl_xor(v, 1);
                        acc[m][n][r] = odd ? (v2 * sn + v * c) : (v * c - v2 * sn);
                    }
            }
        }
    }

#pragma unroll
    for (int m = 0; m < 4; m++)
#pragma unroll
        for (int n = 0; n < 4; n++)
#pragma unroll
            for (int r = 0; r < 4; r++) {
                int row = bm * 128 + wm * 64 + m * 16 + lg * 4 + r;
                int col = bn * 128 + wn * 64 + n * 16 + ln15;
                C[(size_t)row * ldc + col] = (OT)acc[m][n][r];
            }
}

// ---------------- flash attention, causal, GQA rep=4 ----------------
// 512 blocks (LPT decode), 512 threads = 8 waves x 16 q-rows (QBLK=128), KVBLK=64.
// Round-5 schedule (best measured): K+V double-buffered, STAGE issued at top of loop,
// one barrier per tile. 8 waves -> 2 waves/SIMD guaranteed (fixes 1-wave/SIMD stall).
__global__ __launch_bounds__(512) void attn_kernel(const __bf16* __restrict__ qkv,
                                                   const __bf16* __restrict__ vT,
                                                   __bf16* __restrict__ ctx) {
    __shared__ __align__(16) __bf16 Klds[2][64 * 128];   // [kv][d], granule g at g^(kv&7)
    __shared__ __align__(16) __bf16 VTlds[2][128 * 64];  // [d][kv], granule g at g^(d&7)
    __shared__ __align__(16) __bf16 Plds[8][16 * 64];    // per wave [16 q][64 kv], granule g at g^(q&7)

    const int tid = threadIdx.x, lane = tid & 63, w = tid >> 6;  // w = 0..7
    const int ln15 = lane & 15, lg = lane >> 4;
    int i = blockIdx.x, qblk, hb;
    if (i < 256) { qblk = 15 - (i >> 5); hb = i & 31; }
    else { int j = i - 256; qblk = j >> 5; hb = j & 31; }
    const int h = hb >> 1, b = hb & 1;
    const int kvh = h >> 2;
    const int qw0 = qblk * 128 + w * 16;  // 16 rows per wave
    const float c1 = 0.08838834764831845f * 1.4426950408889634f;  // scale * log2(e)

    const __bf16* qbase = qkv + (size_t)(b * 2048 + qw0 + ln15) * 3072 + h * 128;
    bf16x8 aq[4];
#pragma unroll
    for (int c = 0; c < 4; c++)
        aq[c] = *(const bf16x8*)(qbase + c * 32 + lg * 8);

    const __bf16* Kg = qkv + (size_t)(b * 2048) * 3072 + 2048 + kvh * 128;
    const __bf16* Vg = vT + (size_t)((b * 4 + kvh) * 128) * 2048;

    const f32x4 fzero = {0.f, 0.f, 0.f, 0.f};
    float m_run[4], l_run[4];
    f32x4 acc[8];
#pragma unroll
    for (int r = 0; r < 4; r++) { m_run[r] = -1e30f; l_run[r] = 0.f; }
#pragma unroll
    for (int dt = 0; dt < 8; dt++) acc[dt] = fzero;

    const int nt = 2 * qblk + 2;

#define STAGE(buf, t)                                                                     \
    do {                                                                                  \
        const int kb_ = (t) * 64;                                                         \
        _Pragma("unroll") for (int i2 = 0; i2 < 2; i2++) {                                \
            int gid = i2 * 512 + tid;                                                     \
            int kv = gid >> 4, sl = gid & 15;                                             \
            gload16(Kg + (size_t)(kb_ + kv) * 3072 + ((sl ^ (kv & 7)) * 8),               \
                    (char*)Klds[buf] + gid * 16);                                         \
        }                                                                                 \
        _Pragma("unroll") for (int i2 = 0; i2 < 2; i2++) {                                \
            int gid = i2 * 512 + tid;                                                     \
            int d = gid >> 3, sl = gid & 7;                                               \
            gload16(Vg + (size_t)d * 2048 + kb_ + ((sl ^ (d & 7)) * 8),                   \
                    (char*)VTlds[buf] + gid * 16);                                        \
        }                                                                                 \
    } while (0)

    STAGE(0, 0);
    __syncthreads();

    for (int t = 0; t < nt; t++) {
        const int cur = t & 1;
        const int kbase = t * 64;
        if (t + 1 < nt) STAGE(cur ^ 1, t + 1);  // prefetch next tile (overlaps full compute)

        if (kbase <= qw0 + 15) {  // wave has unmasked rows in this tile
            // QK^T : S[16 q][64 kv]
            f32x4 st[4];
#pragma unroll
            for (int ct = 0; ct < 4; ct++) {
                int kv = ct * 16 + ln15;
                f32x4 s = fzero;
#pragma unroll
                for (int c = 0; c < 4; c++) {
                    int g = c * 4 + lg;
                    bf16x8 bk = *(const bf16x8*)&Klds[cur][kv * 128 + ((g ^ (kv & 7)) * 8)];
                    s = __builtin_amdgcn_mfma_f32_16x16x32_bf16(aq[c], bk, s, 0, 0, 0);
                }
                st[ct] = s;
            }
            // causal mask (diagonal tiles only)
            if (kbase + 63 > qw0) {
#pragma unroll
                for (int ct = 0; ct < 4; ct++) {
                    int kvi = kbase + ct * 16 + ln15;
#pragma unroll
                    for (int r = 0; r < 4; r++) {
                        int qi = qw0 + lg * 4 + r;
                        if (kvi > qi) st[ct][r] = -1e30f;
                    }
                }
            }
            // ---- softmax: 4 rows' chains interleaved for ILP ----
            float tm[4];
#pragma unroll
            for (int r = 0; r < 4; r++)
                tm[r] = fmaxf(fmaxf(st[0][r], st[1][r]), fmaxf(st[2][r], st[3][r]));
#pragma unroll
            for (int off = 1; off < 16; off <<= 1)
#pragma unroll
                for (int r = 0; r < 4; r++)
                    tm[r] = fmaxf(tm[r], __shfl_xor(tm[r], off, 16));
            float corr[4];
#pragma unroll
            for (int r = 0; r < 4; r++) {
                float mn = fmaxf(m_run[r], tm[r]);
                corr[r] = exp2f((m_run[r] - mn) * c1);
                m_run[r] = mn;
            }
            float ts[4];
#pragma unroll
            for (int r = 0; r < 4; r++) {
                const int q = lg * 4 + r;
                float s = 0.f;
#pragma unroll
                for (int ct = 0; ct < 4; ct++) {
                    float p = exp2f((st[ct][r] - m_run[r]) * c1);
                    s += p;
                    int pg = ct * 2 + (ln15 >> 3);
                    Plds[w][q * 64 + ((pg ^ (q & 7)) * 8) + (ln15 & 7)] = (__bf16)p;
                }
                ts[r] = s;
            }
#pragma unroll
            for (int off = 1; off < 16; off <<= 1)
#pragma unroll
                for (int r = 0; r < 4; r++)
                    ts[r] += __shfl_xor(ts[r], off, 16);
#pragma unroll
            for (int r = 0; r < 4; r++) l_run[r] = l_run[r] * corr[r] + ts[r];
#pragma unroll
            for (int dt = 0; dt < 8; dt++)
#pragma unroll
                for (int r = 0; r < 4; r++) acc[dt][r] *= corr[r];
            // ---- PV : O[16 q][128 d] += P[16][64] * V[64][128] ----
#pragma unroll
            for (int s2 = 0; s2 < 2; s2++) {
                const int kvg = s2 * 4 + lg;
                bf16x8 pa = *(const bf16x8*)&Plds[w][ln15 * 64 + ((kvg ^ (ln15 & 7)) * 8)];
#pragma unroll
                for (int dt = 0; dt < 8; dt++) {
                    int d = dt * 16 + ln15;
                    bf16x8 bv = *(const bf16x8*)&VTlds[cur][d * 64 + ((kvg ^ (d & 7)) * 8)];
                    acc[dt] = __builtin_amdgcn_mfma_f32_16x16x32_bf16(pa, bv, acc[dt], 0, 0, 0);
                }
            }
        }
        __syncthreads();  // staged K/V drained; buffers swap
    }
#undef STAGE

    // epilogue: O / l -> ctx
    __bf16* crow = ctx + (size_t)(b * 2048 + qw0) * 2048 + h * 128;
#pragma unroll
    for (int dt = 0; dt < 8; dt++)
#pragma unroll
        for (int r = 0; r < 4; r++) {
            float v = acc[dt][r] / l_run[r];
            crow[(size_t)(lg * 4 + r) * 2048 + dt * 16 + ln15] = (__bf16)v;
        }
}

extern "C" void kernel_launch(void* const* d_in, const int* in_sizes, int n_in,
                              void* d_out, int out_size, void* d_ws, size_t ws_size,
                              hipStream_t stream) {
    const float* x = (const float*)d_in[0];
    const float* fc = (const float*)d_in[1];
    const float* fs = (const float*)d_in[2];
    const float* wq = (const float*)d_in[3];
    const float* wk = (const float*)d_in[4];
    const float* wv = (const float*)d_in[5];
    const float* wo = (const float*)d_in[6];
    float* out = (float*)d_out;

    char* ws = (char*)d_ws;
    __bf16* wT  = (__bf16*)ws;                        // [3072][2048]
    __bf16* woT = (__bf16*)(ws + 12582912);           // [2048][2048]
    __bf16* xb  = (__bf16*)(ws + 20971520);           // [4096][2048]
    __bf16* qkv = (__bf16*)(ws + 37748736);           // [4096][3072]
    __bf16* ctx = (__bf16*)(ws + 62914560);           // [4096][2048]
    __bf16* vT  = xb;                                 // reuse xb: [2][4][128][2048]

    prep_kernel<<<18432, 256, 0, stream>>>(x, wq, wk, wv, wo, (u16*)xb, (u16*)wT, (u16*)woT);

    gemm_bt<__bf16, true><<<dim3(24, 32), 256, 0, stream>>>(xb, wT, qkv, 2048, 3072, fc, fs);

    transpose_v<<<dim3(16, 128), 256, 0, stream>>>((const u16*)qkv, (u16*)vT);

    attn_kernel<<<512, 512, 0, stream>>>(qkv, vT, ctx);

    gemm_bt<float, false><<<dim3(16, 32), 256, 0, stream>>>(ctx, woT, out, 2048, 2048, nullptr, nullptr);
}

// Round 11
// 373.553 us; speedup vs baseline: 1.2005x; 1.0694x over previous
//
#include <hip/hip_runtime.h>
#include <hip/hip_bf16.h>

typedef unsigned short u16;
typedef unsigned int u32;
typedef __bf16 bf16x8 __attribute__((ext_vector_type(8)));
typedef float f32x4 __attribute__((ext_vector_type(4)));
typedef u32 u32x2 __attribute__((ext_vector_type(2)));
typedef u32 u32x4 __attribute__((ext_vector_type(4)));

#define AS1 __attribute__((address_space(1)))
#define AS3 __attribute__((address_space(3)))

__device__ __forceinline__ void gload16(const void* gp, void* lp) {
    __builtin_amdgcn_global_load_lds((const AS1 u32*)gp, (AS3 u32*)lp, 16, 0, 0);
}

__device__ __forceinline__ u16 f2b(float f) {
    __bf16 h = (__bf16)f;
    return __builtin_bit_cast(u16, h);
}

__device__ __forceinline__ u32 cvtpk(float lo, float hi) {
    u32 d;
    asm("v_cvt_pk_bf16_f32 %0, %1, %2" : "=v"(d) : "v"(lo), "v"(hi));
    return d;
}

// ---------------- fused prep: x->bf16 convert + 4 weight transposes ----------------
__global__ __launch_bounds__(256) void prep_kernel(const float* __restrict__ x,
                                                   const float* __restrict__ wq,
                                                   const float* __restrict__ wk,
                                                   const float* __restrict__ wv,
                                                   const float* __restrict__ wo,
                                                   u16* __restrict__ xb,
                                                   u16* __restrict__ wT,
                                                   u16* __restrict__ woT) {
    __shared__ u16 tile[32][33];
    const int bid = blockIdx.x, tid = threadIdx.x;
    if (bid < 8192) {
        int i = bid * 256 + tid;
        f32x4 v = *(const f32x4*)(x + (size_t)i * 4);
        u32x2 o;
        o[0] = (u32)f2b(v[0]) | ((u32)f2b(v[1]) << 16);
        o[1] = (u32)f2b(v[2]) | ((u32)f2b(v[3]) << 16);
        *(u32x2*)(xb + (size_t)i * 4) = o;
        return;
    }
    const float* in;
    u16* out;
    int C, t;
    if (bid < 12288) { t = bid - 8192; in = wq; out = wT; C = 2048; }
    else if (bid < 13312) { t = bid - 12288; in = wk; out = wT + 2048 * 2048; C = 512; }
    else if (bid < 14336) { t = bid - 13312; in = wv; out = wT + 2560 * 2048; C = 512; }
    else { t = bid - 14336; in = wo; out = woT; C = 2048; }
    const int nbx = C >> 5;
    const int bx = (t % nbx) * 32, by = (t / nbx) * 32;
    const int tx = tid & 31, ty = tid >> 5;
#pragma unroll
    for (int i = 0; i < 32; i += 8)
        tile[ty + i][tx] = f2b(in[(size_t)(by + ty + i) * C + bx + tx]);
    __syncthreads();
#pragma unroll
    for (int i = 0; i < 32; i += 8)
        out[(size_t)(bx + ty + i) * 2048 + by + tx] = tile[tx][ty + i];
}

// ---------------- transpose V section of qkv -> vT[b][kvh][d][s] ----------------
__global__ __launch_bounds__(256) void transpose_v(const u16* __restrict__ qkv,
                                                   u16* __restrict__ vT) {
    __shared__ u16 tile[32][33];
    const int bx = blockIdx.x * 32;
    const int by = blockIdx.y * 32;
    const int tx = threadIdx.x & 31, ty = threadIdx.x >> 5;
#pragma unroll
    for (int i = 0; i < 32; i += 8)
        tile[ty + i][tx] = qkv[(size_t)(by + ty + i) * 3072 + 2560 + bx + tx];
    __syncthreads();
    const int b = by >> 11, s0 = by & 2047;
#pragma unroll
    for (int i = 0; i < 32; i += 8)
        vT[(size_t)(b * 512 + bx + ty + i) * 2048 + s0 + tx] = tile[tx][ty + i];
}

// ---------------- GEMM: C[M][ldc slice] = A[M][K] * Bt[N][K]^T, bf16 in, OT out ----------------
template <typename OT, bool ROPE>
__global__ __launch_bounds__(256) void gemm_bt(const __bf16* __restrict__ A,
                                               const __bf16* __restrict__ Bt,
                                               OT* __restrict__ C,
                                               int K, int ldc,
                                               const float* __restrict__ fc,
                                               const float* __restrict__ fs) {
    __shared__ __align__(16) __bf16 Al[128 * 32];
    __shared__ __align__(16) __bf16 Bl[128 * 32];
    const int tid = threadIdx.x;
    const int lane = tid & 63, w = tid >> 6;
    const int wm = w >> 1, wn = w & 1;
    const int ln15 = lane & 15, lg = lane >> 4;
    const int nwg = gridDim.x * gridDim.y;
    const int lid = blockIdx.y * gridDim.x + blockIdx.x;
    const int swz = (lid & 7) * (nwg >> 3) + (lid >> 3);
    const int bm = swz / gridDim.x, bn = swz % gridDim.x;

    const f32x4 fzero = {0.f, 0.f, 0.f, 0.f};
    f32x4 acc[4][4];
#pragma unroll
    for (int m = 0; m < 4; m++)
#pragma unroll
        for (int n = 0; n < 4; n++) acc[m][n] = fzero;

    const __bf16* Ab = A + (size_t)(bm * 128) * K;
    const __bf16* Bb = Bt + (size_t)(bn * 128) * K;

    for (int k0 = 0; k0 < K; k0 += 32) {
#pragma unroll
        for (int i = 0; i < 2; i++) {
            int gid = i * 256 + tid;
            int row = gid >> 2, gc = gid & 3;
            gload16(Ab + (size_t)row * K + k0 + gc * 8, (char*)Al + gid * 16);
            gload16(Bb + (size_t)row * K + k0 + gc * 8, (char*)Bl + gid * 16);
        }
        __syncthreads();
        bf16x8 af[4], bfr[4];
#pragma unroll
        for (int m = 0; m < 4; m++)
            af[m] = *(const bf16x8*)&Al[(wm * 64 + m * 16 + ln15) * 32 + lg * 8];
#pragma unroll
        for (int n = 0; n < 4; n++)
            bfr[n] = *(const bf16x8*)&Bl[(wn * 64 + n * 16 + ln15) * 32 + lg * 8];
#pragma unroll
        for (int m = 0; m < 4; m++)
#pragma unroll
            for (int n = 0; n < 4; n++)
                acc[m][n] = __builtin_amdgcn_mfma_f32_16x16x32_bf16(af[m], bfr[n], acc[m][n], 0, 0, 0);
        __syncthreads();
    }

    if (ROPE) {
#pragma unroll
        for (int n = 0; n < 4; n++) {
            const int col = bn * 128 + wn * 64 + n * 16 + ln15;
            if (col < 2560) {
                const int p = (col & 127) >> 1;
                const bool odd = (col & 1) != 0;
#pragma unroll
                for (int m = 0; m < 4; m++)
#pragma unroll
                    for (int r = 0; r < 4; r++) {
                        const int row = bm * 128 + wm * 64 + m * 16 + lg * 4 + r;
                        const int sp = row & 2047;
                        float c = fc[sp * 64 + p];
                        float sn = fs[sp * 64 + p];
                        float v = acc[m][n][r];
                        float v2 = __shfl_xor(v, 1);
                        acc[m][n][r] = odd ? (v2 * sn + v * c) : (v * c - v2 * sn);
                    }
            }
        }
    }

#pragma unroll
    for (int m = 0; m < 4; m++)
#pragma unroll
        for (int n = 0; n < 4; n++)
#pragma unroll
            for (int r = 0; r < 4; r++) {
                int row = bm * 128 + wm * 64 + m * 16 + lg * 4 + r;
                int col = bn * 128 + wn * 64 + n * 16 + ln15;
                C[(size_t)row * ldc + col] = (OT)acc[m][n][r];
            }
}

// ---------------- flash attention, causal, GQA rep=4 ----------------
// 512 blocks (LPT decode), 512 threads = 8 waves x 16 q-rows, KVBLK=64.
// Swapped QK^T (mfma(K,Q)) -> per-lane in-register softmax (q = ln15); P packed
// in-register (cvt_pk + shfl) feeding PV's A-operand directly. No Plds. LDS 64 KB.
__global__ __launch_bounds__(512) void attn_kernel(const __bf16* __restrict__ qkv,
                                                   const __bf16* __restrict__ vT,
                                                   __bf16* __restrict__ ctx) {
    __shared__ __align__(16) __bf16 Klds[2][64 * 128];   // [kv][d], granule g at g^(kv&7)
    __shared__ __align__(16) __bf16 VTlds[2][128 * 64];  // [d][kv], granule g at g^(d&7)

    const int tid = threadIdx.x, lane = tid & 63, w = tid >> 6;  // w = 0..7
    const int ln15 = lane & 15, lg = (lane >> 4) & 3;
    int i = blockIdx.x, qblk, hb;
    if (i < 256) { qblk = 15 - (i >> 5); hb = i & 31; }
    else { int j = i - 256; qblk = j >> 5; hb = j & 31; }
    const int h = hb >> 1, b = hb & 1;
    const int kvh = h >> 2;
    const int qw0 = qblk * 128 + w * 16;  // 16 rows per wave; this lane's row: qw0 + ln15
    const float c1 = 0.08838834764831845f * 1.4426950408889634f;  // scale * log2(e)

    // Q as B-operand fragment (col = q = ln15, k-chunks c)
    const __bf16* qbase = qkv + (size_t)(b * 2048 + qw0 + ln15) * 3072 + h * 128;
    bf16x8 aq[4];
#pragma unroll
    for (int c = 0; c < 4; c++)
        aq[c] = *(const bf16x8*)(qbase + c * 32 + lg * 8);

    const __bf16* Kg = qkv + (size_t)(b * 2048) * 3072 + 2048 + kvh * 128;
    const __bf16* Vg = vT + (size_t)((b * 4 + kvh) * 128) * 2048;

    const f32x4 fzero = {0.f, 0.f, 0.f, 0.f};
    float m_run = -1e30f, l_run = 0.f;  // per-lane: row q = qw0 + ln15
    f32x4 acc[8];                       // O rows q = lg*4+r, col d = dt*16+ln15
#pragma unroll
    for (int dt = 0; dt < 8; dt++) acc[dt] = fzero;

    // shfl source lanes for P-fragment build
    const int L0 = ln15 + ((lane & 16) << 1);  // ln15 + (lg&1)*32
    const int L1 = L0 + 16;
    const bool selhi = (lane & 32) != 0;  // lg>>1

    const int nt = 2 * qblk + 2;

#define STAGE(buf, t)                                                                     \
    do {                                                                                  \
        const int kb_ = (t) * 64;                                                         \
        _Pragma("unroll") for (int i2 = 0; i2 < 2; i2++) {                                \
            int gid = i2 * 512 + tid;                                                     \
            int kv = gid >> 4, sl = gid & 15;                                             \
            gload16(Kg + (size_t)(kb_ + kv) * 3072 + ((sl ^ (kv & 7)) * 8),               \
                    (char*)Klds[buf] + gid * 16);                                         \
        }                                                                                 \
        _Pragma("unroll") for (int i2 = 0; i2 < 2; i2++) {                                \
            int gid = i2 * 512 + tid;                                                     \
            int d = gid >> 3, sl = gid & 7;                                               \
            gload16(Vg + (size_t)d * 2048 + kb_ + ((sl ^ (d & 7)) * 8),                   \
                    (char*)VTlds[buf] + gid * 16);                                        \
        }                                                                                 \
    } while (0)

    STAGE(0, 0);
    __syncthreads();

    for (int t = 0; t < nt; t++) {
        const int cur = t & 1;
        const int kbase = t * 64;
        if (t + 1 < nt) STAGE(cur ^ 1, t + 1);  // prefetch next tile (overlaps full compute)

        if (kbase <= qw0 + 15) {  // wave-uniform active test
            // QK^T swapped: st[ct] = S^T slice; lane holds q=ln15, kv = kbase+ct*16+lg*4+r
            f32x4 st[4];
#pragma unroll
            for (int ct = 0; ct < 4; ct++) {
                int kv = ct * 16 + ln15;
                f32x4 s = fzero;
#pragma unroll
                for (int c = 0; c < 4; c++) {
                    int g = c * 4 + lg;
                    bf16x8 bk = *(const bf16x8*)&Klds[cur][kv * 128 + ((g ^ (kv & 7)) * 8)];
                    s = __builtin_amdgcn_mfma_f32_16x16x32_bf16(bk, aq[c], s, 0, 0, 0);
                }
                st[ct] = s;
            }
            // causal mask (diagonal tiles only)
            if (kbase + 63 > qw0) {
                const int qi = qw0 + ln15;
#pragma unroll
                for (int ct = 0; ct < 4; ct++)
#pragma unroll
                    for (int r = 0; r < 4; r++) {
                        int kvi = kbase + ct * 16 + lg * 4 + r;
                        if (kvi > qi) st[ct][r] = -1e30f;
                    }
            }
            // ---- in-register softmax (per-lane row q = ln15) ----
            f32x4 t4 = st[0];
#pragma unroll
            for (int ct = 1; ct < 4; ct++)
#pragma unroll
                for (int r = 0; r < 4; r++) t4[r] = fmaxf(t4[r], st[ct][r]);
            float m0 = fmaxf(fmaxf(t4[0], t4[1]), fmaxf(t4[2], t4[3]));
            m0 = fmaxf(m0, __shfl_xor(m0, 16));
            m0 = fmaxf(m0, __shfl_xor(m0, 32));
            float mn = fmaxf(m_run, m0);
            float corr = exp2f((m_run - mn) * c1);
            m_run = mn;
            float p[4][4];
            f32x4 s4 = fzero;
#pragma unroll
            for (int ct = 0; ct < 4; ct++)
#pragma unroll
                for (int r = 0; r < 4; r++) {
                    p[ct][r] = exp2f((st[ct][r] - mn) * c1);
                    s4[r] += p[ct][r];
                }
            float ssum = (s4[0] + s4[1]) + (s4[2] + s4[3]);
            ssum += __shfl_xor(ssum, 16);
            ssum += __shfl_xor(ssum, 32);
            l_run = l_run * corr + ssum;
            // pack P to bf16 pairs: P32[ct] covers kv = ct*16 + lg*4 + {0..3}
            u32 P32[4][2];
#pragma unroll
            for (int ct = 0; ct < 4; ct++) {
                P32[ct][0] = cvtpk(p[ct][0], p[ct][1]);
                P32[ct][1] = cvtpk(p[ct][2], p[ct][3]);
            }
            // rescale accumulator (rows q = lg*4+r; corr lives at lane ln15 = q, lg-uniform)
            float corrR[4];
#pragma unroll
            for (int r = 0; r < 4; r++) corrR[r] = __shfl(corr, lg * 4 + r);
#pragma unroll
            for (int dt = 0; dt < 8; dt++)
#pragma unroll
                for (int r = 0; r < 4; r++) acc[dt][r] *= corrR[r];
            // ---- PV: A-frag = P (row q=ln15, k = kv = s2*32 + lg*8 + j) via shfl ----
#pragma unroll
            for (int s2 = 0; s2 < 2; s2++) {
                int b00 = __shfl((int)P32[s2 * 2][0], L0);
                int b01 = __shfl((int)P32[s2 * 2][1], L0);
                int b10 = __shfl((int)P32[s2 * 2 + 1][0], L0);
                int b11 = __shfl((int)P32[s2 * 2 + 1][1], L0);
                int c00 = __shfl((int)P32[s2 * 2][0], L1);
                int c01 = __shfl((int)P32[s2 * 2][1], L1);
                int c10 = __shfl((int)P32[s2 * 2 + 1][0], L1);
                int c11 = __shfl((int)P32[s2 * 2 + 1][1], L1);
                u32x4 av;
                av[0] = selhi ? (u32)b10 : (u32)b00;
                av[1] = selhi ? (u32)b11 : (u32)b01;
                av[2] = selhi ? (u32)c10 : (u32)c00;
                av[3] = selhi ? (u32)c11 : (u32)c01;
                bf16x8 pa = __builtin_bit_cast(bf16x8, av);
                const int kvg = s2 * 4 + lg;
#pragma unroll
                for (int dt = 0; dt < 8; dt++) {
                    int d = dt * 16 + ln15;
                    bf16x8 bv = *(const bf16x8*)&VTlds[cur][d * 64 + ((kvg ^ (d & 7)) * 8)];
                    acc[dt] = __builtin_amdgcn_mfma_f32_16x16x32_bf16(pa, bv, acc[dt], 0, 0, 0);
                }
            }
        }
        __syncthreads();  // staged K/V drained; buffers swap
    }
#undef STAGE

    // epilogue: O / l -> ctx  (l lives at lane ln15 = q, lg-uniform)
    float lR[4];
#pragma unroll
    for (int r = 0; r < 4; r++) lR[r] = __shfl(l_run, lg * 4 + r);
    __bf16* crow = ctx + (size_t)(b * 2048 + qw0) * 2048 + h * 128;
#pragma unroll
    for (int dt = 0; dt < 8; dt++)
#pragma unroll
        for (int r = 0; r < 4; r++) {
            float v = acc[dt][r] / lR[r];
            crow[(size_t)(lg * 4 + r) * 2048 + dt * 16 + ln15] = (__bf16)v;
        }
}

extern "C" void kernel_launch(void* const* d_in, const int* in_sizes, int n_in,
                              void* d_out, int out_size, void* d_ws, size_t ws_size,
                              hipStream_t stream) {
    const float* x = (const float*)d_in[0];
    const float* fc = (const float*)d_in[1];
    const float* fs = (const float*)d_in[2];
    const float* wq = (const float*)d_in[3];
    const float* wk = (const float*)d_in[4];
    const float* wv = (const float*)d_in[5];
    const float* wo = (const float*)d_in[6];
    float* out = (float*)d_out;

    char* ws = (char*)d_ws;
    __bf16* wT  = (__bf16*)ws;                        // [3072][2048]
    __bf16* woT = (__bf16*)(ws + 12582912);           // [2048][2048]
    __bf16* xb  = (__bf16*)(ws + 20971520);           // [4096][2048]
    __bf16* qkv = (__bf16*)(ws + 37748736);           // [4096][3072]
    __bf16* ctx = (__bf16*)(ws + 62914560);           // [4096][2048]
    __bf16* vT  = xb;                                 // reuse xb: [2][4][128][2048]

    prep_kernel<<<18432, 256, 0, stream>>>(x, wq, wk, wv, wo, (u16*)xb, (u16*)wT, (u16*)woT);

    gemm_bt<__bf16, true><<<dim3(24, 32), 256, 0, stream>>>(xb, wT, qkv, 2048, 3072, fc, fs);

    transpose_v<<<dim3(16, 128), 256, 0, stream>>>((const u16*)qkv, (u16*)vT);

    attn_kernel<<<512, 512, 0, stream>>>(qkv, vT, ctx);

    gemm_bt<float, false><<<dim3(16, 32), 256, 0, stream>>>(ctx, woT, out, 2048, 2048, nullptr, nullptr);
}